// Round 1
// baseline (503.360 us; speedup 1.0000x reference)
//
#include <hip/hip_runtime.h>
#include <hip/hip_bf16.h>

typedef __attribute__((ext_vector_type(8))) short short8;
typedef __attribute__((ext_vector_type(4))) float floatx4;

#define N_BI 256
#define N_BS 256
#define LI 36
#define LS 30

constexpr int CHW    = 40;                    // padded chunk width (bf16) -> 80 B rows
constexpr int XCH_B  = LI * CHW * 2;          // 2880 B per X chunk
constexpr int YCH_B  = LS * CHW * 2;          // 2400 B per Y chunk
constexpr int XU     = XCH_B / 16;            // 180 16B units
constexpr int YU     = YCH_B / 16;            // 150
constexpr int IBK    = 4, JBK = 4;            // i/j per block
constexpr int XUNITS = IBK * XU;              // 720
constexpr int YUNITS = JBK * YU;              // 600
constexpr int UNITS  = XUNITS + YUNITS;       // 1320
constexpr int TBUF_B = IBK * XCH_B + JBK * YCH_B; // 21120 B per t-buffer

constexpr long long X2_ELEMS = (long long)N_BI * 16 * LI * CHW;  // 5,898,240
constexpr long long Y2_ELEMS = (long long)N_BS * 16 * LS * CHW;  // 4,915,200
constexpr long long PART_OFF = 0;                                 // 4096 doubles
constexpr long long X2_OFF   = 32768;
constexpr long long Y2_OFF   = X2_OFF + X2_ELEMS * 2;

// ---- async global->LDS, 16B per lane (CK-style addrspace casts) ----
__device__ __forceinline__ void gld16(const void* g, void* l) {
  __builtin_amdgcn_global_load_lds(
      (const __attribute__((address_space(1))) void*)(g),
      (__attribute__((address_space(3))) void*)(unsigned int)(unsigned long long)(l),
      16, 0, 0);
}

// ---- precompute: bf16 hi/lo split, chunked+padded layout ----
// X2[i][c][p][cc]: c<8 -> hi of k=(c&7)*32+cc ; c>=8 -> lo. cc>=32 zero pad.
__global__ void adl_build_x2(const float* __restrict__ src, __hip_bfloat16* __restrict__ dst) {
  long long idx = (long long)blockIdx.x * 256 + threadIdx.x;
  if (idx >= X2_ELEMS) return;
  int cc = (int)(idx % CHW);
  int p  = (int)((idx / CHW) % LI);
  int c  = (int)((idx / (CHW * LI)) % 16);
  int i  = (int)(idx / ((long long)CHW * LI * 16));
  float outv = 0.f;
  if (cc < 32) {
    int k = (c & 7) * 32 + cc;
    float x = src[((long long)i * 37 + (p + 1)) * 256 + k];
    float hf = __bfloat162float(__float2bfloat16(x));
    outv = (c < 8) ? hf : (x - hf);
  }
  dst[idx] = __float2bfloat16(outv);
}

__global__ void adl_build_y2(const float* __restrict__ src, __hip_bfloat16* __restrict__ dst) {
  long long idx = (long long)blockIdx.x * 256 + threadIdx.x;
  if (idx >= Y2_ELEMS) return;
  int cc = (int)(idx % CHW);
  int q  = (int)((idx / CHW) % LS);
  int c  = (int)((idx / (CHW * LS)) % 16);
  int j  = (int)(idx / ((long long)CHW * LS * 16));
  float outv = 0.f;
  if (cc < 32) {
    int k = (c & 7) * 32 + cc;
    float y = src[((long long)j * 31 + (q + 1)) * 256 + k];
    float hf = __bfloat162float(__float2bfloat16(y));
    outv = (c < 8) ? hf : (y - hf);
  }
  dst[idx] = __float2bfloat16(outv);
}

// ---- main fused kernel ----
__global__ __launch_bounds__(512) void adl_main(
    const char* __restrict__ X2g, const char* __restrict__ Y2g,
    const float* __restrict__ teacher, const int* __restrict__ im_len,
    const int* __restrict__ s_len, double* __restrict__ partials) {
  __shared__ __align__(16) char lds[2 * TBUF_B];
  __shared__ double wsum[8];

  const int bid = blockIdx.x;
  const int ig = bid >> 6, jg = bid & 63;
  const int i0 = ig * IBK, j0 = jg * JBK;
  const int tid = (int)threadIdx.x;
  const int w = tid >> 6, l = tid & 63;
  const int iw = w >> 1;            // wave's i within block
  const int jw0 = (w & 1) * 2;      // wave's first j within block
  const int col = l & 15, kg = l >> 4;

  floatx4 acc[2][2][3];
#pragma unroll
  for (int jj = 0; jj < 2; ++jj)
#pragma unroll
    for (int qt = 0; qt < 2; ++qt)
#pragma unroll
      for (int pt = 0; pt < 3; ++pt)
        acc[jj][qt][pt] = (floatx4){0.f, 0.f, 0.f, 0.f};

  // stage one t-step: X chunks for 4 i's, Y chunks for 4 j's
  auto stage = [&](char* buf, int t) {
    int cx = (t < 16) ? (t & 7) : (8 + (t & 7));
    int cy = (t < 8) ? t : ((t < 16) ? (8 + (t & 7)) : (t & 7));
#pragma unroll
    for (int s = 0; s < 3; ++s) {
      int slot = w * 3 + s;
      int u = slot * 64 + l;
      char* lb = buf + slot * 1024;   // wave-uniform base; HW dest = base + lane*16
      if (u < UNITS) {
        const char* g;
        if (u < XUNITS) {
          int ii = u / XU, rem = u % XU;
          g = X2g + (long long)((i0 + ii) * 16 + cx) * XCH_B + rem * 16;
        } else {
          int uy = u - XUNITS;
          int jj = uy / YU, rem = uy % YU;
          g = Y2g + (long long)((j0 + jj) * 16 + cy) * YCH_B + rem * 16;
        }
        gld16(g, lb);
      }
    }
  };

  stage(lds, 0);

#pragma unroll 2
  for (int t = 0; t < 24; ++t) {
    __syncthreads();   // compiler drains vmcnt before barrier -> tile t visible
    if (t + 1 < 24) stage(lds + ((t + 1) & 1) * TBUF_B, t + 1);
    const char* cur = lds + (t & 1) * TBUF_B;

    // B-operand frags (X, N=p)
    short8 bfrag[3];
    const char* Xb = cur + iw * XCH_B;
#pragma unroll
    for (int pt = 0; pt < 3; ++pt) {
      int p = pt * 16 + col; p = p > 35 ? 35 : p;   // clamp: cols>=36 ignored later
      bfrag[pt] = *(const short8*)(Xb + p * 80 + kg * 16);
    }
    // A-operand frags (Y, M=q)
    short8 afrag[2][2];
#pragma unroll
    for (int jj = 0; jj < 2; ++jj) {
      const char* Yb = cur + IBK * XCH_B + (jw0 + jj) * YCH_B;
#pragma unroll
      for (int qt = 0; qt < 2; ++qt) {
        int q = qt * 16 + col; q = q > 29 ? 29 : q;
        afrag[jj][qt] = *(const short8*)(Yb + q * 80 + kg * 16);
      }
    }
#pragma unroll
    for (int jj = 0; jj < 2; ++jj)
#pragma unroll
      for (int qt = 0; qt < 2; ++qt)
#pragma unroll
        for (int pt = 0; pt < 3; ++pt)
          acc[jj][qt][pt] = __builtin_amdgcn_mfma_f32_16x16x32_bf16(
              afrag[jj][qt], bfrag[pt], acc[jj][qt][pt], 0, 0, 0);
  }

  // ---- epilogue: per q-row lse + teacher KL ----
  const float scale = 0.0625f;  // 1/sqrt(256)
  const int i = i0 + iw;
  const int ilim = min(im_len[i] - 1, LI);
  float part = 0.f;

#pragma unroll
  for (int jj = 0; jj < 2; ++jj) {
    const int j = j0 + jw0 + jj;
    const int sl = min(s_len[j] - 1, LS);
    const float* Tb = teacher + ((long long)i * N_BS + j) * (LS * LI);
#pragma unroll
    for (int qt = 0; qt < 2; ++qt) {
#pragma unroll
      for (int r = 0; r < 4; ++r) {
        int q = qt * 16 + 4 * kg + r;        // C layout: row = 4*(lane>>4)+reg
        int tq = q < LS ? q : LS - 1;        // clamp to avoid OOB teacher reads
        float v0 = acc[jj][qt][0][r] * scale;
        float v1 = acc[jj][qt][1][r] * scale;
        float v2 = acc[jj][qt][2][r] * scale;
        int p0 = col, p1 = col + 16, p2 = col + 32;
        bool a2 = p2 < LI;
        bool m0 = p0 < ilim, m1 = p1 < ilim, m2 = p2 < ilim;  // m2 implies a2
        float t0 = Tb[tq * LI + p0];
        float t1 = Tb[tq * LI + p1];
        float t2 = a2 ? Tb[tq * LI + p2] : 0.f;
        float S = fabsf(t0) + fabsf(t1) + fabsf(t2);
        float mx = -3.0e38f;
        if (m0) mx = v0;
        if (m1) mx = fmaxf(mx, v1);
        if (m2) mx = fmaxf(mx, v2);
#pragma unroll
        for (int d = 1; d < 16; d <<= 1) mx = fmaxf(mx, __shfl_xor(mx, d));
        float se = (m0 ? __expf(v0 - mx) : 0.f) + (m1 ? __expf(v1 - mx) : 0.f) +
                   (m2 ? __expf(v2 - mx) : 0.f);
        float g0 = (m0 && t0 > 0.f) ? t0 : 0.f;
        float g1 = (m1 && t1 > 0.f) ? t1 : 0.f;
        float g2 = (m2 && t2 > 0.f) ? t2 : 0.f;
        float spos = g0 + g1 + g2;
        float tlt = 0.f;
        if (g0 > 0.f) tlt += t0 * __logf(t0);
        if (g1 > 0.f) tlt += t1 * __logf(t1);
        if (g2 > 0.f) tlt += t2 * __logf(t2);
        float cnum = g0 * v0 + g1 * v1 + g2 * v2;
        float r0 = S, r1 = se, r2 = spos, r3 = tlt, r4 = cnum;
#pragma unroll
        for (int d = 1; d < 16; d <<= 1) {
          r0 += __shfl_xor(r0, d);
          r1 += __shfl_xor(r1, d);
          r2 += __shfl_xor(r2, d);
          r3 += __shfl_xor(r3, d);
          r4 += __shfl_xor(r4, d);
        }
        float lse = mx + __logf(r1);
        float Sb = fmaxf(r0, 1e-12f);
        float row = (r3 - r4 + (lse - __logf(Sb)) * r2) / Sb;
        if (q < LS && q < sl && col == 0) part += row;
      }
    }
  }

  // wave + block reduce -> one f64 partial per block (deterministic)
#pragma unroll
  for (int d = 1; d < 64; d <<= 1) part += __shfl_xor(part, d);
  if (l == 0) wsum[w] = (double)part;
  __syncthreads();
  if (tid == 0) {
    double s = 0.0;
#pragma unroll
    for (int k = 0; k < 8; ++k) s += wsum[k];
    partials[bid] = s;
  }
}

// ---- finalize: fixed-order reduction + n_rows ----
__global__ void adl_finalize(const double* __restrict__ partials,
                             const int* __restrict__ s_len, float* __restrict__ out) {
  __shared__ double sd[256];
  __shared__ double sn[256];
  int t = (int)threadIdx.x;
  double s = 0.0;
  for (int k = t; k < 4096; k += 256) s += partials[k];
  sd[t] = s;
  sn[t] = (double)min(s_len[t] - 1, LS);
  __syncthreads();
  for (int step = 128; step > 0; step >>= 1) {
    if (t < step) { sd[t] += sd[t + step]; sn[t] += sn[t + step]; }
    __syncthreads();
  }
  if (t == 0) out[0] = (float)(sd[0] / (sn[0] * 256.0));
}

extern "C" void kernel_launch(void* const* d_in, const int* in_sizes, int n_in,
                              void* d_out, int out_size, void* d_ws, size_t ws_size,
                              hipStream_t stream) {
  (void)in_sizes; (void)n_in; (void)out_size; (void)ws_size;
  const float* im     = (const float*)d_in[0];
  const float* ss     = (const float*)d_in[1];
  const int*   imlen  = (const int*)d_in[2];
  const int*   slen   = (const int*)d_in[3];
  const float* teach  = (const float*)d_in[4];
  float* out = (float*)d_out;
  char* ws = (char*)d_ws;
  double* partials = (double*)(ws + PART_OFF);
  __hip_bfloat16* X2 = (__hip_bfloat16*)(ws + X2_OFF);
  __hip_bfloat16* Y2 = (__hip_bfloat16*)(ws + Y2_OFF);

  adl_build_x2<<<(int)((X2_ELEMS + 255) / 256), 256, 0, stream>>>(im, X2);
  adl_build_y2<<<(int)((Y2_ELEMS + 255) / 256), 256, 0, stream>>>(ss, Y2);
  adl_main<<<4096, 512, 0, stream>>>((const char*)X2, (const char*)Y2,
                                     teach, imlen, slen, partials);
  adl_finalize<<<1, 256, 0, stream>>>(partials, slen, out);
}

// Round 2
// 239.944 us; speedup vs baseline: 2.0978x; 2.0978x over previous
//
#include <hip/hip_runtime.h>
#include <hip/hip_bf16.h>

typedef __attribute__((ext_vector_type(8))) short short8;
typedef __attribute__((ext_vector_type(4))) float floatx4;

#define N_BI 256
#define N_BS 256
#define LI 36
#define LS 30

constexpr int CHW    = 40;                    // padded chunk width (bf16) -> 80 B rows
constexpr int XCH_B  = LI * CHW * 2;          // 2880 B per X chunk
constexpr int YCH_B  = LS * CHW * 2;          // 2400 B per Y chunk
constexpr int XU     = XCH_B / 16;            // 180 16B units
constexpr int YU     = YCH_B / 16;            // 150
constexpr int IBK    = 4, JBK = 4;
constexpr int XUNITS = IBK * XU;              // 720
constexpr int UNITS  = XUNITS + JBK * YU;     // 1320
constexpr int TBUF_B = IBK * XCH_B + JBK * YCH_B; // 21120 B per t-buffer
constexpr int NSTEP  = 24;

constexpr long long X2_ELEMS = (long long)N_BI * 16 * LI * CHW;
constexpr long long Y2_ELEMS = (long long)N_BS * 16 * LS * CHW;
constexpr long long X2_OFF   = 32768;
constexpr long long Y2_OFF   = X2_OFF + X2_ELEMS * 2;

__device__ __forceinline__ void gld16(const void* g, void* l) {
  __builtin_amdgcn_global_load_lds(
      (const __attribute__((address_space(1))) void*)(g),
      (__attribute__((address_space(3))) void*)(unsigned int)(unsigned long long)(l),
      16, 0, 0);
}

// ---- precompute: bf16 hi/lo split, chunked+padded layout (unchanged, verified) ----
__global__ void adl_build_x2(const float* __restrict__ src, __hip_bfloat16* __restrict__ dst) {
  long long idx = (long long)blockIdx.x * 256 + threadIdx.x;
  if (idx >= X2_ELEMS) return;
  int cc = (int)(idx % CHW);
  int p  = (int)((idx / CHW) % LI);
  int c  = (int)((idx / (CHW * LI)) % 16);
  int i  = (int)(idx / ((long long)CHW * LI * 16));
  float outv = 0.f;
  if (cc < 32) {
    int k = (c & 7) * 32 + cc;
    float x = src[((long long)i * 37 + (p + 1)) * 256 + k];
    float hf = __bfloat162float(__float2bfloat16(x));
    outv = (c < 8) ? hf : (x - hf);
  }
  dst[idx] = __float2bfloat16(outv);
}

__global__ void adl_build_y2(const float* __restrict__ src, __hip_bfloat16* __restrict__ dst) {
  long long idx = (long long)blockIdx.x * 256 + threadIdx.x;
  if (idx >= Y2_ELEMS) return;
  int cc = (int)(idx % CHW);
  int q  = (int)((idx / CHW) % LS);
  int c  = (int)((idx / (CHW * LS)) % 16);
  int j  = (int)(idx / ((long long)CHW * LS * 16));
  float outv = 0.f;
  if (cc < 32) {
    int k = (c & 7) * 32 + cc;
    float y = src[((long long)j * 31 + (q + 1)) * 256 + k];
    float hf = __bfloat162float(__float2bfloat16(y));
    outv = (c < 8) ? hf : (y - hf);
  }
  dst[idx] = __float2bfloat16(outv);
}

// ---- main fused kernel ----
__global__ __launch_bounds__(512, 4) void adl_main(
    const char* __restrict__ X2g, const char* __restrict__ Y2g,
    const float* __restrict__ teacher, const int* __restrict__ im_len,
    const int* __restrict__ s_len, double* __restrict__ partials) {
  __shared__ __align__(16) char lds[3 * TBUF_B];   // 63360 B, 3-deep pipeline
  __shared__ double wsum[8];

  const int bid = blockIdx.x;
  const int ig = bid >> 6, jg = bid & 63;
  const int i0 = ig * IBK, j0 = jg * JBK;
  const int tid = (int)threadIdx.x;
  const int w = tid >> 6, l = tid & 63;
  const int iw = w >> 1;            // wave's i within block
  const int jw0 = (w & 1) * 2;      // wave's first j within block
  const int col = l & 15, kg = l >> 4;

  // acc[jj][pt][nt] : M = p (rows, in-lane), N = q (cols, lane&15)
  floatx4 acc[2][3][2];
#pragma unroll
  for (int jj = 0; jj < 2; ++jj)
#pragma unroll
    for (int pt = 0; pt < 3; ++pt)
#pragma unroll
      for (int nt = 0; nt < 2; ++nt)
        acc[jj][pt][nt] = (floatx4){0.f, 0.f, 0.f, 0.f};

  // ---- per-lane staging descriptors (computed once) ----
  const char* gsrc[3];
  bool sact[3], sisx[3];
  int  ldst[3];
#pragma unroll
  for (int s = 0; s < 3; ++s) {
    int u = (w * 3 + s) * 64 + l;
    sact[s] = (u < UNITS);
    ldst[s] = (w * 3 + s) * 1024;
    if (u < XUNITS) {
      int ii = u / XU, rem = u % XU;
      gsrc[s] = X2g + (long long)((i0 + ii) * 16) * XCH_B + rem * 16;
      sisx[s] = true;
    } else {
      int uy = (u < UNITS) ? (u - XUNITS) : 0;
      int jb = uy / YU, rem = uy % YU;
      gsrc[s] = Y2g + (long long)((j0 + jb) * 16) * YCH_B + rem * 16;
      sisx[s] = false;
    }
  }

  auto stage = [&](int bi, int t) {
    int cxo = ((t & 7) + ((t >= 16) ? 8 : 0)) * XCH_B;
    int cyo = ((t < 8) ? t : ((t < 16) ? (8 + (t & 7)) : (t & 7))) * YCH_B;
    char* tb = lds + bi * TBUF_B;
#pragma unroll
    for (int s = 0; s < 3; ++s)
      if (sact[s]) gld16(gsrc[s] + (sisx[s] ? cxo : cyo), tb + ldst[s]);
  };

  // ---- fragment LDS byte offsets (within a tile buffer), computed once ----
  int xoff[3];
#pragma unroll
  for (int pt = 0; pt < 3; ++pt) {
    int p = pt * 16 + col; p = p > LI - 1 ? LI - 1 : p;
    xoff[pt] = iw * XCH_B + p * 80 + kg * 16;
  }
  int yoff[2][2];
#pragma unroll
  for (int jj = 0; jj < 2; ++jj)
#pragma unroll
    for (int nt = 0; nt < 2; ++nt) {
      int q = nt * 16 + col; q = q > LS - 1 ? LS - 1 : q;
      yoff[jj][nt] = IBK * XCH_B + (jw0 + jj) * YCH_B + q * 80 + kg * 16;
    }

  // ---- pipelined K-loop: 3 buffers, counted vmcnt, raw barriers ----
  stage(0, 0);
  stage(1, 1);
  asm volatile("s_waitcnt vmcnt(3)" ::: "memory");  // stage(0) landed (own)
  __builtin_amdgcn_s_barrier();                     // everyone's stage(0) landed

#pragma unroll 3
  for (int t = 0; t < NSTEP; ++t) {
    if (t + 2 < NSTEP) stage((t + 2) % 3, t + 2);
    const char* tb = lds + (t % 3) * TBUF_B;
    short8 xf[3];
#pragma unroll
    for (int pt = 0; pt < 3; ++pt) xf[pt] = *(const short8*)(tb + xoff[pt]);
    short8 yf[2][2];
#pragma unroll
    for (int jj = 0; jj < 2; ++jj)
#pragma unroll
      for (int nt = 0; nt < 2; ++nt) yf[jj][nt] = *(const short8*)(tb + yoff[jj][nt]);
#pragma unroll
    for (int jj = 0; jj < 2; ++jj)
#pragma unroll
      for (int pt = 0; pt < 3; ++pt)
#pragma unroll
        for (int nt = 0; nt < 2; ++nt)
          acc[jj][pt][nt] = __builtin_amdgcn_mfma_f32_16x16x32_bf16(
              xf[pt], yf[jj][nt], acc[jj][pt][nt], 0, 0, 0);
    // stage(t+1) must be landed (for all waves) before compute(t+1):
    asm volatile("s_waitcnt vmcnt(3)" ::: "memory");
    __builtin_amdgcn_s_barrier();
  }

  // ---- epilogue: per q-row lse + teacher KL, p in-lane ----
  const float scale = 0.0625f;  // 1/sqrt(256)
  const int i = i0 + iw;
  const int ilim = min(im_len[i] - 1, LI);
  float part = 0.f;
  const floatx4 Tz = (floatx4){0.f, 0.f, 0.f, 0.f};

#pragma unroll
  for (int jj = 0; jj < 2; ++jj) {
    const int j = j0 + jw0 + jj;
    const int sl = min(s_len[j] - 1, LS);
    const float* Tb = teacher + ((long long)i * N_BS + j) * (LS * LI);
    // batch teacher loads for both nt (float4, each element exactly once)
    floatx4 T[2][3];
#pragma unroll
    for (int nt = 0; nt < 2; ++nt) {
      int tq = nt * 16 + col; tq = tq > LS - 1 ? LS - 1 : tq;
      const float* rb = Tb + tq * LI;
      T[nt][0] = *(const floatx4*)(rb + 4 * kg);
      T[nt][1] = *(const floatx4*)(rb + 16 + 4 * kg);
      T[nt][2] = (kg == 0) ? *(const floatx4*)(rb + 32) : Tz;
    }
#pragma unroll
    for (int nt = 0; nt < 2; ++nt) {
      const int q = nt * 16 + col;
      // scaled logits + in-lane masked max (p = pt*16 + 4*kg + r)
      float vv[3][4];
      float mx = -3.0e38f;
#pragma unroll
      for (int pt = 0; pt < 3; ++pt)
#pragma unroll
        for (int r = 0; r < 4; ++r) {
          int p = pt * 16 + 4 * kg + r;
          vv[pt][r] = acc[jj][pt][nt][r] * scale;
          if (p < ilim) mx = fmaxf(mx, vv[pt][r]);
        }
      mx = fmaxf(mx, __shfl_xor(mx, 16));
      mx = fmaxf(mx, __shfl_xor(mx, 32));
      // in-lane sums
      float se = 0.f, S = 0.f, spos = 0.f, tlt = 0.f, cnum = 0.f;
#pragma unroll
      for (int pt = 0; pt < 3; ++pt)
#pragma unroll
        for (int r = 0; r < 4; ++r) {
          int p = pt * 16 + 4 * kg + r;
          bool pv = p < ilim;                 // ilim <= 36 covers structural too
          if (pv) se += __expf(vv[pt][r] - mx);
          float tt = T[nt][pt][r];            // zero where structurally invalid
          S += fabsf(tt);
          if (pv && tt > 0.f) {
            spos += tt;
            tlt += tt * __logf(tt);
            cnum += tt * vv[pt][r];
          }
        }
      // cross-lane (4 kg groups): xor 16, 32
#pragma unroll
      for (int d = 16; d <= 32; d <<= 1) {
        se   += __shfl_xor(se, d);
        S    += __shfl_xor(S, d);
        spos += __shfl_xor(spos, d);
        tlt  += __shfl_xor(tlt, d);
        cnum += __shfl_xor(cnum, d);
      }
      float lse = mx + __logf(se);
      float Sb = fmaxf(S, 1e-12f);
      float row = (tlt - cnum + (lse - __logf(Sb)) * spos) / Sb;
      if (kg == 0 && q < sl) part += row;   // q < sl <= 30 implies q valid
    }
  }

  // wave + block reduce -> one f64 partial per block (deterministic)
#pragma unroll
  for (int d = 1; d < 64; d <<= 1) part += __shfl_xor(part, d);
  if (l == 0) wsum[w] = (double)part;
  __syncthreads();
  if (tid == 0) {
    double s = 0.0;
#pragma unroll
    for (int k = 0; k < 8; ++k) s += wsum[k];
    partials[bid] = s;
  }
}

// ---- finalize: fixed-order reduction + n_rows ----
__global__ void adl_finalize(const double* __restrict__ partials,
                             const int* __restrict__ s_len, float* __restrict__ out) {
  __shared__ double sd[256];
  __shared__ double sn[256];
  int t = (int)threadIdx.x;
  double s = 0.0;
  for (int k = t; k < 4096; k += 256) s += partials[k];
  sd[t] = s;
  sn[t] = (double)min(s_len[t] - 1, LS);
  __syncthreads();
  for (int step = 128; step > 0; step >>= 1) {
    if (t < step) { sd[t] += sd[t + step]; sn[t] += sn[t + step]; }
    __syncthreads();
  }
  if (t == 0) out[0] = (float)(sd[0] / (sn[0] * 256.0));
}

extern "C" void kernel_launch(void* const* d_in, const int* in_sizes, int n_in,
                              void* d_out, int out_size, void* d_ws, size_t ws_size,
                              hipStream_t stream) {
  (void)in_sizes; (void)n_in; (void)out_size; (void)ws_size;
  const float* im     = (const float*)d_in[0];
  const float* ss     = (const float*)d_in[1];
  const int*   imlen  = (const int*)d_in[2];
  const int*   slen   = (const int*)d_in[3];
  const float* teach  = (const float*)d_in[4];
  float* out = (float*)d_out;
  char* ws = (char*)d_ws;
  double* partials = (double*)ws;
  __hip_bfloat16* X2 = (__hip_bfloat16*)(ws + X2_OFF);
  __hip_bfloat16* Y2 = (__hip_bfloat16*)(ws + Y2_OFF);

  adl_build_x2<<<(int)((X2_ELEMS + 255) / 256), 256, 0, stream>>>(im, X2);
  adl_build_y2<<<(int)((Y2_ELEMS + 255) / 256), 256, 0, stream>>>(ss, Y2);
  adl_main<<<4096, 512, 0, stream>>>((const char*)X2, (const char*)Y2,
                                     teach, imlen, slen, partials);
  adl_finalize<<<1, 256, 0, stream>>>(partials, slen, out);
}

// Round 3
// 204.456 us; speedup vs baseline: 2.4620x; 1.1736x over previous
//
#include <hip/hip_runtime.h>
#include <hip/hip_bf16.h>

typedef __attribute__((ext_vector_type(8))) short short8;
typedef __attribute__((ext_vector_type(4))) float floatx4;

#define N_BI 256
#define N_BS 256
#define LI 36
#define LS 30

// CHW=32 (no pad): X chunk = 36*64 = 2304 B, Y chunk = 30*64 = 1920 B.
// Global/LDS layout XOR-swizzled: inner = (row*64 + cc*2) ^ ((row&7)<<4).
constexpr int XCK   = 2304;
constexpr int YCK   = 1920;
constexpr int XSTEP = 2 * XCK;                // 4608 B per i per k-step (h+l)
constexpr int YSTEP = 2 * YCK;                // 3840 B per j per k-step
constexpr int IBK = 4, JBK = 4;
constexpr int XBLK = IBK * XSTEP;             // 18432
constexpr int YBLK = JBK * YSTEP;             // 15360
constexpr int TB   = XBLK + YBLK;             // 33792 B per k-step buffer
constexpr int XUNITS = XBLK / 16;             // 1152
constexpr int UNITS  = TB / 16;               // 2112 = 33 wave-slots

constexpr long long X2_BYTES = (long long)N_BI * 8 * XSTEP;  // 9,437,184
constexpr long long Y2_BYTES = (long long)N_BS * 8 * YSTEP;  // 7,864,320
constexpr long long X2_OFF = 32768;
constexpr long long Y2_OFF = X2_OFF + X2_BYTES;

__device__ __forceinline__ void gld16(const void* g, void* l) {
  __builtin_amdgcn_global_load_lds(
      (const __attribute__((address_space(1))) void*)(g),
      (__attribute__((address_space(3))) void*)(unsigned int)(unsigned long long)(l),
      16, 0, 0);
}

// ---- precompute: bf16 hi/lo split into swizzled chunked layout ----
// X2[i][kc][hl][ (p*64+cc*2)^((p&7)<<4) ]
__global__ void adl_build_x2(const float* __restrict__ src, char* __restrict__ dst) {
  long long e = (long long)blockIdx.x * 256 + threadIdx.x;
  if (e >= (long long)N_BI * 8 * 2 * LI * 32) return;
  int cc = (int)(e & 31);
  long long t = e >> 5;
  int p  = (int)(t % LI); t /= LI;
  int hl = (int)(t & 1);  t >>= 1;
  int kc = (int)(t & 7);
  int i  = (int)(t >> 3);
  float x = src[((long long)i * 37 + p + 1) * 256 + kc * 32 + cc];
  float hf = __bfloat162float(__float2bfloat16(x));
  float v = hl ? (x - hf) : hf;
  long long db = ((long long)(i * 8 + kc) * 2 + hl) * XCK +
                 ((p * 64 + cc * 2) ^ ((p & 7) << 4));
  *(__hip_bfloat16*)(dst + db) = __float2bfloat16(v);
}

__global__ void adl_build_y2(const float* __restrict__ src, char* __restrict__ dst) {
  long long e = (long long)blockIdx.x * 256 + threadIdx.x;
  if (e >= (long long)N_BS * 8 * 2 * LS * 32) return;
  int cc = (int)(e & 31);
  long long t = e >> 5;
  int q  = (int)(t % LS); t /= LS;
  int hl = (int)(t & 1);  t >>= 1;
  int kc = (int)(t & 7);
  int j  = (int)(t >> 3);
  float y = src[((long long)j * 31 + q + 1) * 256 + kc * 32 + cc];
  float hf = __bfloat162float(__float2bfloat16(y));
  float v = hl ? (y - hf) : hf;
  long long db = ((long long)(j * 8 + kc) * 2 + hl) * YCK +
                 ((q * 64 + cc * 2) ^ ((q & 7) << 4));
  *(__hip_bfloat16*)(dst + db) = __float2bfloat16(v);
}

// ---- main fused kernel: 8 k-steps, 3 products/step, double-buffered ----
__global__ __launch_bounds__(512, 4) void adl_main(
    const char* __restrict__ X2g, const char* __restrict__ Y2g,
    const float* __restrict__ teacher, const int* __restrict__ im_len,
    const int* __restrict__ s_len, double* __restrict__ partials) {
  __shared__ __align__(16) char lds[2 * TB];
  __shared__ double wsum[8];

  const int bid = blockIdx.x;
  const int ig = bid >> 6, jg = bid & 63;
  const int i0 = ig * IBK, j0 = jg * JBK;
  const int tid = (int)threadIdx.x;
  const int w = tid >> 6, l = tid & 63;
  const int iw = w >> 1;            // wave's i within block
  const int jw0 = (w & 1) * 2;      // wave's first j within block
  const int col = l & 15, kg = l >> 4;

  floatx4 acc[2][3][2];             // [jj][pt][nt]
#pragma unroll
  for (int jj = 0; jj < 2; ++jj)
#pragma unroll
    for (int pt = 0; pt < 3; ++pt)
#pragma unroll
      for (int nt = 0; nt < 2; ++nt)
        acc[jj][pt][nt] = (floatx4){0.f, 0.f, 0.f, 0.f};

  // ---- staging descriptors: 5 slots; dest = u*16 (wave-uniform base + lane*16) ----
  const char* cur[5];
  int str[5];
  char* ldsb[5];
#pragma unroll
  for (int s = 0; s < 5; ++s) {
    int u = s * 512 + tid;
    ldsb[s] = lds + (s * 512 + w * 64) * 16;   // lane-invariant base
    if (u < XUNITS) {
      int ii = u / 288, r = u % 288;
      cur[s] = X2g + (long long)(i0 + ii) * (8 * XSTEP) + r * 16;
      str[s] = XSTEP;
    } else {
      int v = u - XUNITS; v = v > 959 ? 959 : v;   // clamp (inactive lanes)
      int jj = v / 240, r = v % 240;
      cur[s] = Y2g + (long long)(j0 + jj) * (8 * YSTEP) + r * 16;
      str[s] = YSTEP;
    }
  }

  auto stage = [&](int bi) {
#pragma unroll
    for (int s = 0; s < 5; ++s) {
      if (s < 4 || w == 0) {
        gld16(cur[s], ldsb[s] + bi * TB);
        cur[s] += str[s];
      }
    }
  };

  // ---- fragment offsets within a tile buffer (h; l = +XCK/+YCK) ----
  int xoh[3];
#pragma unroll
  for (int pt = 0; pt < 3; ++pt) {
    int p = pt * 16 + col; p = p > LI - 1 ? LI - 1 : p;
    xoh[pt] = iw * XSTEP + ((p * 64 + kg * 16) ^ ((p & 7) << 4));
  }
  int yoh[2][2];
#pragma unroll
  for (int jj = 0; jj < 2; ++jj)
#pragma unroll
    for (int nt = 0; nt < 2; ++nt) {
      int q = nt * 16 + col; q = q > LS - 1 ? LS - 1 : q;
      yoh[jj][nt] = XBLK + (jw0 + jj) * YSTEP + ((q * 64 + kg * 16) ^ ((q & 7) << 4));
    }

  // ---- K-loop: 8 steps, stage(t+1) early, 3 product phases, 1 barrier/step ----
  stage(0);
  __syncthreads();

#pragma unroll
  for (int kc = 0; kc < 8; ++kc) {
    if (kc < 7) stage((kc + 1) & 1);
    const char* tb = lds + (kc & 1) * TB;

    short8 xh[3], yh[2][2];
#pragma unroll
    for (int pt = 0; pt < 3; ++pt) xh[pt] = *(const short8*)(tb + xoh[pt]);
#pragma unroll
    for (int jj = 0; jj < 2; ++jj)
#pragma unroll
      for (int nt = 0; nt < 2; ++nt) yh[jj][nt] = *(const short8*)(tb + yoh[jj][nt]);
    __builtin_amdgcn_s_setprio(1);
#pragma unroll
    for (int jj = 0; jj < 2; ++jj)
#pragma unroll
      for (int pt = 0; pt < 3; ++pt)
#pragma unroll
        for (int nt = 0; nt < 2; ++nt)
          acc[jj][pt][nt] = __builtin_amdgcn_mfma_f32_16x16x32_bf16(
              xh[pt], yh[jj][nt], acc[jj][pt][nt], 0, 0, 0);
    __builtin_amdgcn_s_setprio(0);

    short8 xl[3];
#pragma unroll
    for (int pt = 0; pt < 3; ++pt) xl[pt] = *(const short8*)(tb + xoh[pt] + XCK);
    __builtin_amdgcn_s_setprio(1);
#pragma unroll
    for (int jj = 0; jj < 2; ++jj)
#pragma unroll
      for (int pt = 0; pt < 3; ++pt)
#pragma unroll
        for (int nt = 0; nt < 2; ++nt)
          acc[jj][pt][nt] = __builtin_amdgcn_mfma_f32_16x16x32_bf16(
              xl[pt], yh[jj][nt], acc[jj][pt][nt], 0, 0, 0);
    __builtin_amdgcn_s_setprio(0);

    short8 yl[2][2];
#pragma unroll
    for (int jj = 0; jj < 2; ++jj)
#pragma unroll
      for (int nt = 0; nt < 2; ++nt)
        yl[jj][nt] = *(const short8*)(tb + yoh[jj][nt] + YCK);
    __builtin_amdgcn_s_setprio(1);
#pragma unroll
    for (int jj = 0; jj < 2; ++jj)
#pragma unroll
      for (int pt = 0; pt < 3; ++pt)
#pragma unroll
        for (int nt = 0; nt < 2; ++nt)
          acc[jj][pt][nt] = __builtin_amdgcn_mfma_f32_16x16x32_bf16(
              xh[pt], yl[jj][nt], acc[jj][pt][nt], 0, 0, 0);
    __builtin_amdgcn_s_setprio(0);

    __syncthreads();   // drains vmcnt(0): stage(kc+1) landed; LDS reads consumed
  }

  // ---- epilogue: per q-row lse + teacher KL, p in-lane (verified in R2) ----
  const float scale = 0.0625f;  // 1/sqrt(256)
  const int i = i0 + iw;
  const int ilim = min(im_len[i] - 1, LI);
  float part = 0.f;
  const floatx4 Tz = (floatx4){0.f, 0.f, 0.f, 0.f};

#pragma unroll
  for (int jj = 0; jj < 2; ++jj) {
    const int j = j0 + jw0 + jj;
    const int sl = min(s_len[j] - 1, LS);
    const float* Tb = teacher + ((long long)i * N_BS + j) * (LS * LI);
    floatx4 T[2][3];
#pragma unroll
    for (int nt = 0; nt < 2; ++nt) {
      int tq = nt * 16 + col; tq = tq > LS - 1 ? LS - 1 : tq;
      const float* rb = Tb + tq * LI;
      T[nt][0] = *(const floatx4*)(rb + 4 * kg);
      T[nt][1] = *(const floatx4*)(rb + 16 + 4 * kg);
      T[nt][2] = (kg == 0) ? *(const floatx4*)(rb + 32) : Tz;
    }
#pragma unroll
    for (int nt = 0; nt < 2; ++nt) {
      const int q = nt * 16 + col;
      float vv[3][4];
      float mx = -3.0e38f;
#pragma unroll
      for (int pt = 0; pt < 3; ++pt)
#pragma unroll
        for (int r = 0; r < 4; ++r) {
          int p = pt * 16 + 4 * kg + r;
          vv[pt][r] = acc[jj][pt][nt][r] * scale;
          if (p < ilim) mx = fmaxf(mx, vv[pt][r]);
        }
      mx = fmaxf(mx, __shfl_xor(mx, 16));
      mx = fmaxf(mx, __shfl_xor(mx, 32));
      float se = 0.f, S = 0.f, spos = 0.f, tlt = 0.f, cnum = 0.f;
#pragma unroll
      for (int pt = 0; pt < 3; ++pt)
#pragma unroll
        for (int r = 0; r < 4; ++r) {
          int p = pt * 16 + 4 * kg + r;
          bool pv = p < ilim;
          if (pv) se += __expf(vv[pt][r] - mx);
          float tt = T[nt][pt][r];
          S += fabsf(tt);
          if (pv && tt > 0.f) {
            spos += tt;
            tlt += tt * __logf(tt);
            cnum += tt * vv[pt][r];
          }
        }
#pragma unroll
      for (int d = 16; d <= 32; d <<= 1) {
        se   += __shfl_xor(se, d);
        S    += __shfl_xor(S, d);
        spos += __shfl_xor(spos, d);
        tlt  += __shfl_xor(tlt, d);
        cnum += __shfl_xor(cnum, d);
      }
      float lse = mx + __logf(se);
      float Sb = fmaxf(S, 1e-12f);
      float row = (tlt - cnum + (lse - __logf(Sb)) * spos) / Sb;
      if (kg == 0 && q < sl) part += row;
    }
  }

#pragma unroll
  for (int d = 1; d < 64; d <<= 1) part += __shfl_xor(part, d);
  if (l == 0) wsum[w] = (double)part;
  __syncthreads();
  if (tid == 0) {
    double s = 0.0;
#pragma unroll
    for (int k = 0; k < 8; ++k) s += wsum[k];
    partials[bid] = s;
  }
}

// ---- finalize: fixed-order reduction + n_rows ----
__global__ void adl_finalize(const double* __restrict__ partials,
                             const int* __restrict__ s_len, float* __restrict__ out) {
  __shared__ double sd[256];
  __shared__ double sn[256];
  int t = (int)threadIdx.x;
  double s = 0.0;
  for (int k = t; k < 4096; k += 256) s += partials[k];
  sd[t] = s;
  sn[t] = (double)min(s_len[t] - 1, LS);
  __syncthreads();
  for (int step = 128; step > 0; step >>= 1) {
    if (t < step) { sd[t] += sd[t + step]; sn[t] += sn[t + step]; }
    __syncthreads();
  }
  if (t == 0) out[0] = (float)(sd[0] / (sn[0] * 256.0));
}

extern "C" void kernel_launch(void* const* d_in, const int* in_sizes, int n_in,
                              void* d_out, int out_size, void* d_ws, size_t ws_size,
                              hipStream_t stream) {
  (void)in_sizes; (void)n_in; (void)out_size; (void)ws_size;
  const float* im     = (const float*)d_in[0];
  const float* ss     = (const float*)d_in[1];
  const int*   imlen  = (const int*)d_in[2];
  const int*   slen   = (const int*)d_in[3];
  const float* teach  = (const float*)d_in[4];
  float* out = (float*)d_out;
  char* ws = (char*)d_ws;
  double* partials = (double*)ws;
  char* X2 = ws + X2_OFF;
  char* Y2 = ws + Y2_OFF;

  long long xe = (long long)N_BI * 8 * 2 * LI * 32;
  long long ye = (long long)N_BS * 8 * 2 * LS * 32;
  adl_build_x2<<<(int)((xe + 255) / 256), 256, 0, stream>>>(im, X2);
  adl_build_y2<<<(int)((ye + 255) / 256), 256, 0, stream>>>(ss, Y2);
  adl_main<<<4096, 512, 0, stream>>>(X2, Y2, teach, imlen, slen, partials);
  adl_finalize<<<1, 256, 0, stream>>>(partials, slen, out);
}